// Round 1
// baseline (451.722 us; speedup 1.0000x reference)
//
#include <hip/hip_runtime.h>
#include <stdint.h>

// Problem constants
#define NPIX   32768      // 32 * 32 * 32 flattened vectors
#define DIM    256        // embedding dim
#define KCODE  1024       // codebook entries
#define BSTRIDE 262144    // 256*32*32 floats per batch in NCHW
#define OUT0_N 8388608    // 32*256*32*32
// d_out layout: [0 .. 8388607] quantized_st, [8388608] loss, [8388609 ..] indices(float)
//
// NEW STRUCTURE (round 0 of this session):
//   vq_sums   : exact numpy-pairwise sx/se (unchanged, proven) + init loss/mcount
//   vq_prep_x : transpose+bf16-split x -> XH,XL planes [n][d]  (SCRATCH IN d_out!)
//   vq_prep_e : bf16-split codebook -> EH,EL [k][d] (in ws)
//   vq_gemm   : MFMA screening GEMM (xh*eh + xl*eh + xh*el), per-pixel (min,sec,k)
//               on v = -2m+se; gap>MARGIN -> provably-unique exact argmin -> idx[]
//               else pixel appended to mlist (near-ties, ~5%)
//   vq_select : exact full 1024-code rescan (bit-exact ascending fmac chain,
//               fold fma(-2,m,sx)+se, tie->smaller k) for mlist pixels
//   vq_write  : gather + straight-through + loss partials (reads idx[])
//   vq_loss   : finalize
//
// Soundness of fast path: exclusion of code j needs v_j - v_min > 2*ULP_d + 2*eps_v
// ~= 1.1e-4 (ULP_d = 3.05e-5 at d~256; eps_v <= 2*eps_m ~ 2.4e-5 worst-case for this
// data). MARGIN = 3e-4 gives 2.7x slack. Near-tie pixels are resolved fully exactly.
// DEBUG LEVER: MARGIN 1e30f forces all pixels through vq_select (exact, ~170us).
#define MARGIN 3e-4f

typedef __bf16 bf16x8 __attribute__((ext_vector_type(8)));
typedef float  f32x4  __attribute__((ext_vector_type(4)));

#define GLOAD_LDS16(src, dst)                                                       \
    __builtin_amdgcn_global_load_lds(                                               \
        (const __attribute__((address_space(1))) unsigned int*)(src),               \
        (__attribute__((address_space(3))) unsigned int*)(dst), 16, 0, 0)

// ---------------------------------------------------------------------------
// One numpy pw128 accumulator chain (proven): r = v0^2; r += v_i^2 (15 adds).
// ---------------------------------------------------------------------------
__device__ __forceinline__ float sqchain(const float* __restrict__ base, int stride, int c0) {
    float v = base[(size_t)c0 * stride];
    float r = __fmul_rn(v, v);
#pragma unroll
    for (int i = 1; i < 16; ++i) {
        float u = base[(size_t)(c0 + 8 * i) * stride];
        r = __fadd_rn(r, __fmul_rn(u, u));
    }
    return r;
}

// ---------------------------------------------------------------------------
// Kernel 1: numpy-pairwise sums of squares (PROVEN — do not modify the tree).
// Also inits the loss accumulator and the multi-pixel-list counter.
// ---------------------------------------------------------------------------
__global__ void vq_sums(const float* __restrict__ in, const float* __restrict__ emb,
                        float* __restrict__ sx_arr, float* __restrict__ se_arr,
                        float* __restrict__ loss_acc, unsigned int* __restrict__ mcount) {
    const int tid  = threadIdx.x;
    const int wave = tid >> 6;
    const int lane = tid & 63;
    const int jg   = lane >> 4;
    const int p    = lane & 15;
    const int n    = blockIdx.x * 64 + wave * 16 + p;
    if (blockIdx.x == 0 && tid == 0) { *loss_acc = 0.0f; *mcount = 0u; }

    const float* base;
    int stride;
    if (n < NPIX) {
        base = in + (size_t)(n >> 10) * BSTRIDE + (n & 1023);
        stride = 1024;
    } else {
        base = emb + (size_t)(n - NPIX) * DIM;
        stride = 1;
    }
    const int c0 = 2 * jg;
    float glo = __fadd_rn(sqchain(base, stride, c0),       sqchain(base, stride, c0 + 1));
    float ghi = __fadd_rn(sqchain(base, stride, 128 + c0), sqchain(base, stride, 128 + c0 + 1));
    glo = __fadd_rn(glo, __shfl_xor(glo, 16, 64));
    glo = __fadd_rn(glo, __shfl_xor(glo, 32, 64));
    ghi = __fadd_rn(ghi, __shfl_xor(ghi, 16, 64));
    ghi = __fadd_rn(ghi, __shfl_xor(ghi, 32, 64));
    float s = __fadd_rn(glo, ghi);

    if (jg == 0) {
        if (n < NPIX) sx_arr[n] = s;
        else          se_arr[n - NPIX] = s;
    }
}

// RNE fp32 -> bf16 split: x ~= hi + lo, |x - hi - lo| <= |x|*2^-16
__device__ __forceinline__ void bfsplit(float x, unsigned short& h, unsigned short& l) {
    unsigned u  = __float_as_uint(x);
    unsigned rh = u + 0x7FFFu + ((u >> 16) & 1u);
    h = (unsigned short)(rh >> 16);
    float xl = x - __uint_as_float((rh >> 16) << 16);   // exact in fp32
    unsigned ul = __float_as_uint(xl);
    l = (unsigned short)((ul + 0x7FFFu + ((ul >> 16) & 1u)) >> 16);
}

// ---------------------------------------------------------------------------
// Kernel 2a: transpose + split x (NCHW fp32) -> XH,XL bf16 planes [n][d].
// XH/XL live in d_out (33.55MB exact) — overwritten later by vq_write.
// grid = 512 n-tiles * 4 d-tiles, 64x64 tiles through LDS.
// ---------------------------------------------------------------------------
__global__ void vq_prep_x(const float* __restrict__ in,
                          unsigned short* __restrict__ XH, unsigned short* __restrict__ XL) {
    __shared__ float t[64][65];
    const int bx = blockIdx.x;
    const int tn = bx >> 2, td = bx & 3;
    const int n0 = tn << 6, d0 = td << 6;
    const int b = n0 >> 10, hw0 = n0 & 1023;
    const int tid = threadIdx.x;
    const int m4 = (tid & 15) << 2, dl = tid >> 4;
    const float* base = in + (size_t)b * BSTRIDE + hw0;
#pragma unroll
    for (int p = 0; p < 4; ++p) {
        int d = dl + (p << 4);
        float4 v = *(const float4*)(base + (size_t)(d0 + d) * 1024 + m4);
        t[d][m4] = v.x; t[d][m4 + 1] = v.y; t[d][m4 + 2] = v.z; t[d][m4 + 3] = v.w;
    }
    __syncthreads();
    const int m = tid >> 2, dg = (tid & 3) << 4;
    unsigned hp[8], lp[8];
#pragma unroll
    for (int j = 0; j < 8; ++j) {
        unsigned short h0, l0, h1, l1;
        bfsplit(t[dg + 2 * j][m], h0, l0);
        bfsplit(t[dg + 2 * j + 1][m], h1, l1);
        hp[j] = (unsigned)h0 | ((unsigned)h1 << 16);
        lp[j] = (unsigned)l0 | ((unsigned)l1 << 16);
    }
    size_t ro = (size_t)(n0 + m) * 256 + d0 + dg;   // ushort element offset
    uint4 H0 = {hp[0], hp[1], hp[2], hp[3]}, H1 = {hp[4], hp[5], hp[6], hp[7]};
    uint4 L0 = {lp[0], lp[1], lp[2], lp[3]}, L1 = {lp[4], lp[5], lp[6], lp[7]};
    *(uint4*)(XH + ro) = H0; *(uint4*)(XH + ro + 8) = H1;
    *(uint4*)(XL + ro) = L0; *(uint4*)(XL + ro + 8) = L1;
}

// ---------------------------------------------------------------------------
// Kernel 2b: split codebook -> EH,EL bf16 [k][d] (natural layout, no transpose).
// ---------------------------------------------------------------------------
__global__ void vq_prep_e(const float* __restrict__ emb,
                          unsigned short* __restrict__ EH, unsigned short* __restrict__ EL) {
    const size_t base = ((size_t)blockIdx.x * 256 + threadIdx.x) * 16;
#pragma unroll
    for (int q = 0; q < 4; ++q) {
        float4 v = *(const float4*)(emb + base + q * 4);
        unsigned short h0, l0, h1, l1, h2, l2, h3, l3;
        bfsplit(v.x, h0, l0); bfsplit(v.y, h1, l1);
        bfsplit(v.z, h2, l2); bfsplit(v.w, h3, l3);
        uint2 H = {(unsigned)h0 | ((unsigned)h1 << 16), (unsigned)h2 | ((unsigned)h3 << 16)};
        uint2 L = {(unsigned)l0 | ((unsigned)l1 << 16), (unsigned)l2 | ((unsigned)l3 << 16)};
        *(uint2*)(EH + base + q * 4) = H;
        *(uint2*)(EL + base + q * 4) = L;
    }
}

// ---------------------------------------------------------------------------
// Kernel 3: MFMA screening GEMM + per-pixel (min, sec, argmin-k) on v=-2m+se.
// Block: 64 pixels x all 1024 codes, 4 waves, K=256. LDS 80KB dynamic:
//   [0,32K)  xh plane [64][256] bf16, XOR-swizzled: byte(m,kb)=m*512+(kb^((m&7)<<4))
//   [32K,64K) xl plane (same layout)
//   [64K,72K) eh chunk [128][32] bf16, slot-swizzled: slot=s^((n>>1)&3)
//   [72K,80K) el chunk (same)
// All staging via global_load_lds width=16 with pre-swizzled SOURCE addresses
// (linear LDS dest, per m104/m173). Fragment ds_read_b128 is conflict-free
// (2-way only) by construction. MFMA: f32_16x16x32_bf16, D row=(l>>4)*4+r (pixel),
// col=l&15 (code) [m89-verified C/D layout].
// ---------------------------------------------------------------------------
__global__ __launch_bounds__(256, 2)
void vq_gemm(const unsigned short* __restrict__ XH, const unsigned short* __restrict__ XL,
             const unsigned short* __restrict__ EH, const unsigned short* __restrict__ EL,
             const float* __restrict__ se_arr,
             int* __restrict__ idx, int* __restrict__ mlist, unsigned int* __restrict__ mcount) {
    extern __shared__ char smem[];
    const int tid  = threadIdx.x;
    const int w    = tid >> 6;          // wave 0..3
    const int lane = tid & 63;
    const int l15  = lane & 15;
    const int lg   = lane >> 4;         // 0..3
    const int n0   = blockIdx.x << 6;   // 64 pixels per block

    // ---- stage x planes (once): waves 0,1 -> XH bytes [0,32K); 2,3 -> XL ----
    {
        const unsigned short* XP = (w < 2) ? XH : XL;
        for (int q = 0; q < 16; ++q) {
            const unsigned o  = (unsigned)(w * 16 + q) << 10;       // uniform dest base
            const unsigned po = (o + (unsigned)lane * 16) & 32767u; // within plane
            const unsigned m  = po >> 9;
            const unsigned kb = (po & 511u) ^ ((m & 7u) << 4);      // pre-swizzled source
            GLOAD_LDS16((const char*)XP + ((size_t)(n0 + m) << 9) + kb, smem + o);
        }
    }

    // ---- es lane-constant decode: wave {0,1}->eh rows [0,64)/[64,128), {2,3}->el ----
    unsigned es_n[4], es_ps[4];
#pragma unroll
    for (int q = 0; q < 4; ++q) {
        unsigned o = ((unsigned)(w & 1) << 12) + ((unsigned)q << 10) + (unsigned)lane * 16;
        unsigned n = o >> 6, s = (o >> 4) & 3u;
        es_n[q]  = n;
        es_ps[q] = (s ^ ((n >> 1) & 3u)) << 4;
    }
    const char* EP = (const char*)((w < 2) ? EH : EL);
    const unsigned es_dst = 65536u + ((unsigned)(w >> 1) << 13) + ((unsigned)(w & 1) << 12);

    // running per-lane triples: 16 pixels (mf,r), codes of this lane
    float rv[16], rs[16]; int rk[16];
#pragma unroll
    for (int i = 0; i < 16; ++i) { rv[i] = __builtin_inff(); rs[i] = __builtin_inff(); rk[i] = 0; }

    for (int nb = 0; nb < 8; ++nb) {
        const int c0 = nb << 7;
        const float sev0 = se_arr[c0 + w * 32 + l15];
        const float sev1 = se_arr[c0 + w * 32 + 16 + l15];
        f32x4 acc[4][2];
#pragma unroll
        for (int mf = 0; mf < 4; ++mf)
#pragma unroll
            for (int nf = 0; nf < 2; ++nf) { f32x4 z = {0.f, 0.f, 0.f, 0.f}; acc[mf][nf] = z; }

        for (int kt = 0; kt < 8; ++kt) {
            __syncthreads();   // prior es readers done; (first iter: drains x-stage too)
#pragma unroll
            for (int q = 0; q < 4; ++q) {
                const char* src = EP + ((size_t)(c0 + es_n[q]) << 9) + ((unsigned)kt << 6) + es_ps[q];
                GLOAD_LDS16(src, smem + es_dst + ((unsigned)q << 10));
            }
            __syncthreads();   // es visible (vmcnt drained by barrier)

            bf16x8 ah[4], al[4], bh[2], bl[2];
            const unsigned kfrag = ((unsigned)kt << 6) + ((unsigned)lg << 4);
#pragma unroll
            for (int mf = 0; mf < 4; ++mf) {
                const unsigned m   = ((unsigned)mf << 4) + (unsigned)l15;
                const unsigned off = (m << 9) + (kfrag ^ ((m & 7u) << 4));
                ah[mf] = *(const bf16x8*)(smem + off);
                al[mf] = *(const bf16x8*)(smem + 32768 + off);
            }
#pragma unroll
            for (int nf = 0; nf < 2; ++nf) {
                const unsigned nw  = ((unsigned)w << 5) + ((unsigned)nf << 4) + (unsigned)l15;
                const unsigned off = 65536u + (nw << 6) + (((unsigned)lg ^ ((nw >> 1) & 3u)) << 4);
                bh[nf] = *(const bf16x8*)(smem + off);
                bl[nf] = *(const bf16x8*)(smem + 8192 + off);
            }
#pragma unroll
            for (int mf = 0; mf < 4; ++mf)
#pragma unroll
                for (int nf = 0; nf < 2; ++nf) {
                    acc[mf][nf] = __builtin_amdgcn_mfma_f32_16x16x32_bf16(ah[mf], bh[nf], acc[mf][nf], 0, 0, 0);
                    acc[mf][nf] = __builtin_amdgcn_mfma_f32_16x16x32_bf16(al[mf], bh[nf], acc[mf][nf], 0, 0, 0);
                    acc[mf][nf] = __builtin_amdgcn_mfma_f32_16x16x32_bf16(ah[mf], bl[nf], acc[mf][nf], 0, 0, 0);
                }
        }

        // fold chunk: v = -2*m + se; merge into running (min,sec,k); k ascending
#pragma unroll
        for (int mf = 0; mf < 4; ++mf)
#pragma unroll
            for (int r = 0; r < 4; ++r) {
                const int t = mf * 4 + r;
#pragma unroll
                for (int nf = 0; nf < 2; ++nf) {
                    float v = __fmaf_rn(-2.f, acc[mf][nf][r], nf ? sev1 : sev0);
                    int   k = c0 + w * 32 + (nf << 4) + l15;
                    if (v < rv[t]) { rs[t] = rv[t]; rv[t] = v; rk[t] = k; }
                    else           { rs[t] = fminf(rs[t], v); }
                }
            }
    }

    // cross-lane reduce within 16-lane groups (lanes hold different codes, same pixel)
#pragma unroll
    for (int t = 0; t < 16; ++t) {
        float v = rv[t], s = rs[t]; int k = rk[t];
#pragma unroll
        for (int mm = 1; mm < 16; mm <<= 1) {
            float ov = __shfl_xor(v, mm, 16);
            float os = __shfl_xor(s, mm, 16);
            int   ok = __shfl_xor(k, mm, 16);
            float ns = fminf(fminf(s, os), fmaxf(v, ov));
            if (ov < v || (ov == v && ok < k)) { v = ov; k = ok; }
            s = ns;
        }
        rv[t] = v; rs[t] = s; rk[t] = k;
    }

    __syncthreads();   // all es/x reads done — safe to alias es region
    float* vmin_s = (float*)(smem + 65536);
    int*   kmin_s = (int*)(smem + 65536 + 1024);
    float* vsec_s = (float*)(smem + 65536 + 2048);
    if (l15 == 0) {
#pragma unroll
        for (int mf = 0; mf < 4; ++mf)
#pragma unroll
            for (int r = 0; r < 4; ++r) {
                int p = mf * 16 + lg * 4 + r;
                vmin_s[p * 4 + w] = rv[mf * 4 + r];
                kmin_s[p * 4 + w] = rk[mf * 4 + r];
                vsec_s[p * 4 + w] = rs[mf * 4 + r];
            }
    }
    __syncthreads();
    if (tid < 64) {
        float v = vmin_s[tid * 4]; int k = kmin_s[tid * 4]; float s = vsec_s[tid * 4];
#pragma unroll
        for (int ww = 1; ww < 4; ++ww) {
            float ov = vmin_s[tid * 4 + ww]; int ok = kmin_s[tid * 4 + ww]; float os = vsec_s[tid * 4 + ww];
            float ns = fminf(fminf(s, os), fmaxf(v, ov));
            if (ov < v || (ov == v && ok < k)) { v = ov; k = ok; }
            s = ns;
        }
        if (s - v > MARGIN) {
            idx[n0 + tid] = k;               // provably-unique exact argmin
        } else {
            unsigned pos = atomicAdd(mcount, 1u);
            mlist[pos] = n0 + tid;           // near-tie: exact rescan
        }
    }
}

// ---------------------------------------------------------------------------
// Kernel 4: exact rescan for near-tie pixels. 8 pixels/block, 32 threads/pixel,
// 32 codes/thread. Bit-exact: ascending-d fmac chain per code, fold
// fma(-2,m,sx)+se, tie -> smaller k via packed (bits(d)<<32|k) min (d>0 always).
// ---------------------------------------------------------------------------
__global__ void vq_select(const float* __restrict__ in, const float* __restrict__ emb,
                          const float* __restrict__ sx_arr, const float* __restrict__ se_arr,
                          const int* __restrict__ mlist, const unsigned int* __restrict__ mcount,
                          int* __restrict__ idx) {
    __shared__ float xrow[8][260];
    __shared__ int   nlist[8];
    __shared__ float sxl[8];
    const unsigned mc = *mcount;
    const int tid = threadIdx.x;
    for (unsigned g = blockIdx.x; g * 8 < mc; g += gridDim.x) {
        __syncthreads();
        if (tid < 8) {
            unsigned ii = g * 8 + tid;
            int n = (ii < mc) ? mlist[ii] : -1;
            nlist[tid] = n;
            sxl[tid] = (n >= 0) ? sx_arr[n] : 0.f;
        }
        __syncthreads();
        const int p = tid >> 5, l32 = tid & 31;
        const int n = nlist[p];
        if (n >= 0) {
            const float* xb = in + (size_t)(n >> 10) * BSTRIDE + (n & 1023);
#pragma unroll
            for (int j = 0; j < 8; ++j) {
                int d = l32 + (j << 5);
                xrow[p][d] = xb[(size_t)d * 1024];
            }
        }
        __syncthreads();
        if (n >= 0) {
            const float sxv = sxl[p];
            unsigned long long best = 0xFFFFFFFFFFFFFFFFull;
            for (int cg = 0; cg < 8; ++cg) {
                const int kb = l32 * 32 + cg * 4;
                const float* e0 = emb + (size_t)(kb + 0) * 256;
                const float* e1 = emb + (size_t)(kb + 1) * 256;
                const float* e2 = emb + (size_t)(kb + 2) * 256;
                const float* e3 = emb + (size_t)(kb + 3) * 256;
                float m0 = 0.f, m1 = 0.f, m2 = 0.f, m3 = 0.f;
                for (int d4 = 0; d4 < 64; ++d4) {
                    float4 xq = *(const float4*)&xrow[p][d4 << 2];
                    float4 q0 = *(const float4*)(e0 + (d4 << 2));
                    float4 q1 = *(const float4*)(e1 + (d4 << 2));
                    float4 q2 = *(const float4*)(e2 + (d4 << 2));
                    float4 q3 = *(const float4*)(e3 + (d4 << 2));
                    m0 = __fmaf_rn(xq.x, q0.x, m0); m0 = __fmaf_rn(xq.y, q0.y, m0);
                    m0 = __fmaf_rn(xq.z, q0.z, m0); m0 = __fmaf_rn(xq.w, q0.w, m0);
                    m1 = __fmaf_rn(xq.x, q1.x, m1); m1 = __fmaf_rn(xq.y, q1.y, m1);
                    m1 = __fmaf_rn(xq.z, q1.z, m1); m1 = __fmaf_rn(xq.w, q1.w, m1);
                    m2 = __fmaf_rn(xq.x, q2.x, m2); m2 = __fmaf_rn(xq.y, q2.y, m2);
                    m2 = __fmaf_rn(xq.z, q2.z, m2); m2 = __fmaf_rn(xq.w, q2.w, m2);
                    m3 = __fmaf_rn(xq.x, q3.x, m3); m3 = __fmaf_rn(xq.y, q3.y, m3);
                    m3 = __fmaf_rn(xq.z, q3.z, m3); m3 = __fmaf_rn(xq.w, q3.w, m3);
                }
                float mm[4] = {m0, m1, m2, m3};
#pragma unroll
                for (int c = 0; c < 4; ++c) {
                    float t1 = __fmaf_rn(-2.f, mm[c], sxv);
                    float dv = __fadd_rn(t1, se_arr[kb + c]);
                    unsigned long long pk =
                        ((unsigned long long)__float_as_uint(dv) << 32) | (unsigned)(kb + c);
                    best = (pk < best) ? pk : best;
                }
            }
            for (int mm2 = 1; mm2 < 32; mm2 <<= 1) {
                unsigned long long ob = __shfl_xor(best, mm2, 32);
                best = (ob < best) ? ob : best;
            }
            if (l32 == 0) idx[n] = (int)(best & 0xFFFFFFFFull);
        }
    }
}

// ---------------------------------------------------------------------------
// Kernel 5: gather quantized rows, straight-through output + indices, loss sum.
// (unchanged except index source). NOTE: overwrites the XH/XL scratch in d_out.
// ---------------------------------------------------------------------------
__global__ void vq_write(const float* __restrict__ in, const float* __restrict__ emb,
                         const int* __restrict__ idx,
                         float* __restrict__ out0, float* __restrict__ out2,
                         float* __restrict__ loss_acc) {
    const int nt = blockIdx.x;
    const int n0 = nt << 7;
    const int b  = n0 >> 10;
    const int hw0 = n0 & 1023;
    const int tid = threadIdx.x;
    const int n_l = tid & 127;
    const int ch0 = tid >> 7;

    const int k = idx[n0 + n_l];
    if (tid < 128) out2[n0 + tid] = (float)k;

    const float* xrow = in  + (size_t)b * BSTRIDE + hw0 + n_l;
    float*       orow = out0 + (size_t)b * BSTRIDE + hw0 + n_l;
    const float* erow = emb + (size_t)k * DIM;

    float lsum = 0.0f;
    for (int it = 0; it < 128; ++it) {
        const int ch = it * 2 + ch0;
        float x = xrow[(size_t)ch * 1024];
        float q = erow[ch];
        float df = __fsub_rn(q, x);
        orow[(size_t)ch * 1024] = __fadd_rn(x, df);
        lsum = __fadd_rn(lsum, __fmul_rn(df, df));
    }
#pragma unroll
    for (int off = 32; off >= 1; off >>= 1)
        lsum += __shfl_down(lsum, off, 64);
    __shared__ float wsum[4];
    if ((tid & 63) == 0) wsum[tid >> 6] = lsum;
    __syncthreads();
    if (tid == 0) {
        float t = wsum[0] + wsum[1] + wsum[2] + wsum[3];
        atomicAdd(loss_acc, t);
    }
}

// ---------------------------------------------------------------------------
// Kernel 6: finalize loss.
// ---------------------------------------------------------------------------
__global__ void vq_loss(const float* __restrict__ loss_acc, float* __restrict__ out1) {
    float s = *loss_acc;
    float e = s * (1.0f / 8388608.0f);
    out1[0] = __fadd_rn(e, __fmul_rn(0.25f, e));
}

extern "C" void kernel_launch(void* const* d_in, const int* in_sizes, int n_in,
                              void* d_out, int out_size, void* d_ws, size_t ws_size,
                              hipStream_t stream) {
    const float* in  = (const float*)d_in[0];
    const float* emb = (const float*)d_in[1];
    float* out = (float*)d_out;

    // workspace layout (~1.4MB)
    float* wsf = (float*)d_ws;
    float* lossacc = wsf;                                 // [0]
    unsigned int* mcount = (unsigned int*)(wsf + 1);      // [1]
    float* sx = wsf + 256;                                // 32768
    float* se = sx + NPIX;                                // 1024
    int*   idx   = (int*)(se + KCODE);                    // 32768
    int*   mlist = idx + NPIX;                            // 32768
    unsigned short* EH = (unsigned short*)(mlist + NPIX); // 1024*256
    unsigned short* EL = EH + (size_t)KCODE * DIM;

    // bf16 x-planes scratch in d_out (exactly the quantized_st region; rewritten by vq_write)
    unsigned short* XH = (unsigned short*)d_out;
    unsigned short* XL = XH + (size_t)NPIX * DIM;

    static bool attr_set = false;
    if (!attr_set) {
        hipFuncSetAttribute((const void*)vq_gemm,
                            hipFuncAttributeMaxDynamicSharedMemorySize, 81920);
        attr_set = true;
    }

    vq_sums<<<(NPIX + KCODE) / 64, 256, 0, stream>>>(in, emb, sx, se, lossacc, mcount);
    vq_prep_x<<<2048, 256, 0, stream>>>(in, XH, XL);
    vq_prep_e<<<64, 256, 0, stream>>>(emb, EH, EL);
    vq_gemm<<<512, 256, 81920, stream>>>(XH, XL, EH, EL, se, idx, mlist, mcount);
    vq_select<<<256, 256, 0, stream>>>(in, emb, sx, se, mlist, mcount, idx);
    vq_write<<<256, 256, 0, stream>>>(in, emb, idx, out, out + OUT0_N + 1, lossacc);
    vq_loss<<<1, 1, 0, stream>>>(lossacc, out + OUT0_N);
}